// Round 7
// baseline (3699.504 us; speedup 1.0000x reference)
//
#include <hip/hip_runtime.h>

#define SEQ 12

typedef __attribute__((ext_vector_type(8))) short bf16x8;   // 8 bf16 bit patterns (4 VGPRs)
typedef __attribute__((ext_vector_type(4))) float f32x4;
typedef __attribute__((ext_vector_type(4))) unsigned short us4;

__device__ __forceinline__ unsigned short f2bf(float x) {
    unsigned u = __builtin_bit_cast(unsigned, x);
    u += 0x7fffu + ((u >> 16) & 1u);            // round-to-nearest-even
    return (unsigned short)(u >> 16);
}
__device__ __forceinline__ float bf2f(unsigned short h) {
    unsigned u = ((unsigned)h) << 16;
    return __builtin_bit_cast(float, u);
}
// packed bf16-pair c-state helpers (keeps c in 32 regs instead of 64)
__device__ __forceinline__ unsigned pack_bf(float lo, float hi) {
    unsigned ul = __builtin_bit_cast(unsigned, lo);
    ul += 0x7fffu + ((ul >> 16) & 1u);
    unsigned uh = __builtin_bit_cast(unsigned, hi);
    uh += 0x7fffu + ((uh >> 16) & 1u);
    return (ul >> 16) | (uh & 0xffff0000u);
}
__device__ __forceinline__ float unpk_lo(unsigned u) { return __builtin_bit_cast(float, u << 16); }
__device__ __forceinline__ float unpk_hi(unsigned u) { return __builtin_bit_cast(float, u & 0xffff0000u); }

__device__ __forceinline__ float sigf(float x) { return 1.0f / (1.0f + __expf(-x)); }
__device__ __forceinline__ float tanhf_(float x) {
    x = fminf(fmaxf(x, -15.0f), 15.0f);
    float e = __expf(2.0f * x);
    return (e - 1.0f) / (e + 1.0f);
}

// ---------------- weight pack kernel ----------------
// d_ws layout (ushort), REPLICATED ncopy times at stride 327680 (640 KB/copy):
//   [0,131072)       L0F  = bf16([W_ih_l0[:,:128] | W_hh_l0])  fused K=256
//   [131072,262144)  L1   = bf16([W_ih_l1 | W_hh_l1])          fused K=256
//   [262144,327680)  INIT = bf16(W_init[:,:128])               K=128
// fragment order: chunk = ((w*4+G)*KK + kk), within chunk: lane*8+j,
//   n = G*128 + w*16 + (lane&15),  k = kk*32 + (lane>>4)*8 + j
__global__ void pack_w(const float* __restrict__ Winit, const float* __restrict__ Wihl0,
                       const float* __restrict__ Whhl0, const float* __restrict__ Wihl1,
                       const float* __restrict__ Whhl1, unsigned short* __restrict__ pk,
                       int ncopy) {
    int id = blockIdx.x * 256 + threadIdx.x;
    if (id >= 327680) return;
    float v;
    if (id < 131072) {                       // L0F, KK=8 (K=256)
        int c = id >> 9, r = id & 511;
        int lane = r >> 3, j = r & 7;
        int kk = c & 7, G = (c >> 3) & 3, w = c >> 5;
        int n = G * 128 + w * 16 + (lane & 15);
        int k = kk * 32 + (lane >> 4) * 8 + j;
        v = (k < 128) ? Wihl0[n * 129 + k] : Whhl0[n * 128 + (k - 128)];
    } else if (id < 262144) {                // L1, KK=8 (K=256)
        int e = id - 131072;
        int c = e >> 9, r = e & 511;
        int lane = r >> 3, j = r & 7;
        int kk = c & 7, G = (c >> 3) & 3, w = c >> 5;
        int n = G * 128 + w * 16 + (lane & 15);
        int k = kk * 32 + (lane >> 4) * 8 + j;
        v = (k < 128) ? Wihl1[n * 128 + k] : Whhl1[n * 128 + (k - 128)];
    } else {                                 // INIT, KK=4 (K=128)
        int e = id - 262144;
        int c = e >> 9, r = e & 511;
        int lane = r >> 3, j = r & 7;
        int kk = c & 3, G = (c >> 2) & 3, w = c >> 4;
        int n = G * 128 + w * 16 + (lane & 15);
        int k = kk * 32 + (lane >> 4) * 8 + j;
        v = Winit[n * 129 + k];
    }
    unsigned short hv = f2bf(v);
    for (int cpy = 0; cpy < ncopy; ++cpy) pk[cpy * 327680 + id] = hv;
}

// per-group helpers. acc[8][4]; halves: rows 0-63 (half 0) / 64-127 (half 1).
#define LOAD_A2(hb, kkl, half) do { _Pragma("unroll") \
    for (int mt = 0; mt < 4; ++mt) \
        a[mt] = *(const bf16x8*)&(hb)[((half) * 64 + mt * 16 + nq) * 128 + ((((kkl) * 4 + quad) ^ nq) << 3)]; \
    } while (0)
#define MFMA_H(slot, half) do { _Pragma("unroll") \
    for (int mt = 0; mt < 4; ++mt) { _Pragma("unroll") \
        for (int G = 0; G < 4; ++G) \
            acc[(half) * 4 + mt][G] = __builtin_amdgcn_mfma_f32_16x16x32_bf16(a[mt], bb[slot][G], acc[(half) * 4 + mt][G], 0, 0, 0); } \
    } while (0)
#define LOAD_B(slot, base, kk) do { _Pragma("unroll") \
    for (int G = 0; G < 4; ++G) \
        bb[slot][G] = *(const bf16x8*)&(base)[((w * 4 + G) * 8 + (kk)) * 512 + lane * 8]; \
    } while (0)
// one K=32 group over both M-halves, then refill the slot 2 groups ahead
#define STEP_G(hb, kkl, slot, rbase, rkk) do { \
    LOAD_A2(hb, kkl, 0); MFMA_H(slot, 0); LOAD_A2(hb, kkl, 1); MFMA_H(slot, 1); \
    LOAD_B(slot, rbase, rkk); } while (0)

// ---------------- fused decoder kernel ----------------
// r7: Mt=128 samples/block (1024 blocks) -> per-sample weight traffic 4 KB/step
// vs r6's 6 KB. Layer0 fused K=256 [x|h1] (x resident in LDS; no pre0 regs).
// acc[8][4] = 128 AGPR; c-state packed bf16-pairs (32 regs). h1/h2 single-
// buffered (4 barriers/step). Weight prefetch ring (distance 2) kept from r6.
__global__ __launch_bounds__(512) __attribute__((amdgpu_waves_per_eu(2, 2)))
void traj_main(const float* __restrict__ fused, const float* __restrict__ intent,
               const float* __restrict__ binit,
               const float* __restrict__ Winit, const float* __restrict__ Wihl0,
               const float* __restrict__ bihl0, const float* __restrict__ bhhl0,
               const float* __restrict__ bihl1, const float* __restrict__ bhhl1,
               const float* __restrict__ Wout, const float* __restrict__ bout,
               const unsigned short* __restrict__ pk, int copyMask,
               float* __restrict__ out, int Bsz) {
    __shared__ __align__(16) unsigned short s_x [128 * 128];   // x-tile, resident all steps
    __shared__ __align__(16) unsigned short s_h1[128 * 128];   // h1 (single buffer)
    __shared__ __align__(16) unsigned short s_h2[128 * 128];   // h2 (single buffer)
    __shared__ __align__(16) unsigned char  s_misc[49152];     // phase A: xi(16K)+cstage(32K); steps: out staging(12K)
    __shared__ float s_wo[256];                                // W_out (2x128)
    __shared__ float s_iv[128];                                // intent per sample

    unsigned short* s_xi = (unsigned short*)s_misc;            // 64x128 bf16
    unsigned short* s_ct = (unsigned short*)(s_misc + 16384);  // 128x128 bf16 c staging
    float* s_out = (float*)s_misc;                             // 128x24 f32 (steps only)

    const int tid = threadIdx.x;
    const int lane = tid & 63;
    const int w = tid >> 6;          // wave 0..7
    const int nq = lane & 15;
    const int quad = lane >> 4;
    const int m0 = blockIdx.x * 128;
    const int Bh = Bsz >> 1;

    const unsigned short* pkb   = pk + (int)(blockIdx.x & copyMask) * 327680;
    const unsigned short* pkL0  = pkb;             // L0F (K=256)
    const unsigned short* pkL1  = pkb + 131072;    // L1  (K=256)
    const unsigned short* pkINI = pkb + 262144;    // INIT (K=128)

    if (tid < 256) s_wo[tid] = Wout[tid];
    if (tid < 128) s_iv[tid] = intent[m0 + tid];
    const float bo = (tid < 256) ? bout[tid & 1] : 0.0f;

    // per-lane column constants (n = G*128 + 16w + nq)
    float bpre[4], bl1[4], wcp[4];
#pragma unroll
    for (int G = 0; G < 4; ++G) {
        int n = G * 128 + w * 16 + nq;
        bpre[G] = bihl0[n] + bhhl0[n];
        bl1[G]  = bihl1[n] + bhhl1[n];
        wcp[G]  = Wihl0[n * 129 + 128];    // intent column of W_ih_l0
    }

    // ---- stage x tile (128 rows) as bf16, swizzled A-layout
#pragma unroll
    for (int it = 0; it < 8; ++it) {
        int f = it * 512 + tid;
        int row = f >> 5, fc = f & 31;
        f32x4 v = *(const f32x4*)(fused + (m0 + row) * 128 + fc * 4);
        us4 u;
#pragma unroll
        for (int j = 0; j < 4; ++j) u[j] = f2bf(v[j]);
        int cp = (fc >> 1) ^ (row & 15);
        *(us4*)&s_x[row * 128 + cp * 8 + (fc & 1) * 4] = u;
    }

    // ---- phase A: two passes (layer 0, layer 1). Each pass: stage 64 init-x
    // rows, GEMM vs W_init (K=128), unpack torch-reshape into h (LDS, swizzled)
    // and c (LDS staging), then read c into packed registers.
    unsigned c1p[16], c2p[16];
    const int kq = w * 16 + nq;
#pragma unroll 1
    for (int pass = 0; pass < 2; ++pass) {
        const int rbase = (pass ? Bh : 0) + (m0 >> 1);
        // stage xi rows [rbase, rbase+64)
#pragma unroll
        for (int it = 0; it < 4; ++it) {
            int f = it * 512 + tid;
            int row = f >> 5, fc = f & 31;
            f32x4 v = *(const f32x4*)(fused + (rbase + row) * 128 + fc * 4);
            us4 u;
#pragma unroll
            for (int j = 0; j < 4; ++j) u[j] = f2bf(v[j]);
            int cp = (fc >> 1) ^ (row & 15);
            *(us4*)&s_xi[row * 128 + cp * 8 + (fc & 1) * 4] = u;
        }
        __syncthreads();   // xi visible (and prior-pass c reads done)

        f32x4 acc2[4][4];
#pragma unroll
        for (int mt = 0; mt < 4; ++mt)
#pragma unroll
            for (int G = 0; G < 4; ++G) acc2[mt][G] = (f32x4){0.f, 0.f, 0.f, 0.f};
#pragma unroll
        for (int kk = 0; kk < 4; ++kk) {
            bf16x8 a2[4], b2[4];
#pragma unroll
            for (int mt = 0; mt < 4; ++mt)
                a2[mt] = *(const bf16x8*)&s_xi[(mt * 16 + nq) * 128 + (((kk * 4 + quad) ^ nq) << 3)];
#pragma unroll
            for (int G = 0; G < 4; ++G)
                b2[G] = *(const bf16x8*)&pkINI[((w * 4 + G) * 4 + kk) * 512 + lane * 8];
#pragma unroll
            for (int mt = 0; mt < 4; ++mt)
#pragma unroll
                for (int G = 0; G < 4; ++G)
                    acc2[mt][G] = __builtin_amdgcn_mfma_f32_16x16x32_bf16(a2[mt], b2[G], acc2[mt][G], 0, 0, 0);
        }
        // bias + intent (init row R = rbase + ri), then unpack:
        // sample ml = 2*ri + (G&1); G0/G1 -> h halves, G2/G3 -> c halves
        unsigned short* hb = pass ? s_h2 : s_h1;
        {
            int kc = kq >> 3, klo = kq & 7;
#pragma unroll
            for (int mt = 0; mt < 4; ++mt)
#pragma unroll
                for (int r = 0; r < 4; ++r) {
                    int ri = mt * 16 + quad * 4 + r;
                    float iv2 = intent[rbase + ri];
#pragma unroll
                    for (int G = 0; G < 4; ++G) {
                        int n = G * 128 + w * 16 + nq;
                        float val = acc2[mt][G][r] + binit[n] + iv2 * Winit[n * 129 + 128];
                        unsigned short hv = f2bf(val);
                        int ml = 2 * ri + (G & 1);
                        if (G < 2) hb[ml * 128 + ((kc ^ (ml & 15)) << 3) + klo] = hv;
                        else       s_ct[ml * 128 + kq] = hv;
                    }
                }
        }
        __syncthreads();   // unpack visible
        // read c for this layer into packed bf16-pair regs
        unsigned* cp_ = pass ? c2p : c1p;
#pragma unroll
        for (int idx = 0; idx < 16; ++idx) {
            int h8 = idx >> 3, mt = (idx >> 1) & 3, rp = idx & 1;
            int ml = h8 * 64 + mt * 16 + quad * 4 + rp * 2;
            unsigned lo16 = s_ct[ml * 128 + kq];
            unsigned hi16 = s_ct[(ml + 1) * 128 + kq];
            cp_[idx] = lo16 | (hi16 << 16);
        }
    }
    __syncthreads();   // c2p reads done before steps alias s_misc as s_out

    // ---- prefetch ring warm-up: first two weight groups of step 0
    bf16x8 bb[2][4];
    LOAD_B(0, pkL0, 0);
    LOAD_B(1, pkL0, 1);

    // ---- 12 decode steps; 16 weight groups/step: L0F k0..7, L1 k0..7
#pragma unroll 1
    for (int s = 0; s < SEQ; ++s) {
        f32x4 acc[8][4];
        bf16x8 a[4];
        // layer0 seed: bpre + iv*wcp
#pragma unroll
        for (int h8 = 0; h8 < 2; ++h8)
#pragma unroll
            for (int mt = 0; mt < 4; ++mt) {
                f32x4 iv4 = *(const f32x4*)&s_iv[h8 * 64 + mt * 16 + quad * 4];
#pragma unroll
                for (int G = 0; G < 4; ++G)
#pragma unroll
                    for (int r = 0; r < 4; ++r)
                        acc[h8 * 4 + mt][G][r] = bpre[G] + iv4[r] * wcp[G];
            }
        // layer0 GEMM: [x | h1] @ L0F^T
        STEP_G(s_x,  0, 0, pkL0, 2);
        STEP_G(s_x,  1, 1, pkL0, 3);
        STEP_G(s_x,  2, 0, pkL0, 4);
        STEP_G(s_x,  3, 1, pkL0, 5);
        STEP_G(s_h1, 0, 0, pkL0, 6);
        STEP_G(s_h1, 1, 1, pkL0, 7);
        STEP_G(s_h1, 2, 0, pkL1, 0);
        STEP_G(s_h1, 3, 1, pkL1, 1);
        __syncthreads();   // B1: all h1 reads done
        // pointwise layer0 -> write new h1 in place
#pragma unroll
        for (int idx = 0; idx < 16; ++idx) {
            int h8 = idx >> 3, mt = (idx >> 1) & 3, rp = idx & 1;
            int am = h8 * 4 + mt, r0 = rp * 2;
            float clo = unpk_lo(c1p[idx]), chi = unpk_hi(c1p[idx]);
            float cnl = sigf(acc[am][1][r0]) * clo + sigf(acc[am][0][r0]) * tanhf_(acc[am][2][r0]);
            float hnl = sigf(acc[am][3][r0]) * tanhf_(cnl);
            float cnh = sigf(acc[am][1][r0 + 1]) * chi + sigf(acc[am][0][r0 + 1]) * tanhf_(acc[am][2][r0 + 1]);
            float hnh = sigf(acc[am][3][r0 + 1]) * tanhf_(cnh);
            c1p[idx] = pack_bf(cnl, cnh);
            int ml = h8 * 64 + mt * 16 + quad * 4 + r0;
            int ch = (w * 2) + (nq >> 3);
            s_h1[ml * 128 + ((ch ^ (ml & 15)) << 3) + (nq & 7)]       = f2bf(hnl);
            s_h1[(ml + 1) * 128 + ((ch ^ ((ml + 1) & 15)) << 3) + (nq & 7)] = f2bf(hnh);
        }
        __syncthreads();   // B2: new h1 visible
        // layer1 GEMM: [h1_new | h2] @ L1^T
#pragma unroll
        for (int am = 0; am < 8; ++am)
#pragma unroll
            for (int G = 0; G < 4; ++G)
                acc[am][G] = (f32x4){bl1[G], bl1[G], bl1[G], bl1[G]};
        STEP_G(s_h1, 0, 0, pkL1, 2);
        STEP_G(s_h1, 1, 1, pkL1, 3);
        STEP_G(s_h1, 2, 0, pkL1, 4);
        STEP_G(s_h1, 3, 1, pkL1, 5);
        STEP_G(s_h2, 0, 0, pkL1, 6);
        STEP_G(s_h2, 1, 1, pkL1, 7);
        STEP_G(s_h2, 2, 0, pkL0, 0);   // next-step L0F k0
        STEP_G(s_h2, 3, 1, pkL0, 1);   // next-step L0F k1
        __syncthreads();   // B3: all h2 reads done
        // pointwise layer1 -> write new h2 in place
#pragma unroll
        for (int idx = 0; idx < 16; ++idx) {
            int h8 = idx >> 3, mt = (idx >> 1) & 3, rp = idx & 1;
            int am = h8 * 4 + mt, r0 = rp * 2;
            float clo = unpk_lo(c2p[idx]), chi = unpk_hi(c2p[idx]);
            float cnl = sigf(acc[am][1][r0]) * clo + sigf(acc[am][0][r0]) * tanhf_(acc[am][2][r0]);
            float hnl = sigf(acc[am][3][r0]) * tanhf_(cnl);
            float cnh = sigf(acc[am][1][r0 + 1]) * chi + sigf(acc[am][0][r0 + 1]) * tanhf_(acc[am][2][r0 + 1]);
            float hnh = sigf(acc[am][3][r0 + 1]) * tanhf_(cnh);
            c2p[idx] = pack_bf(cnl, cnh);
            int ml = h8 * 64 + mt * 16 + quad * 4 + r0;
            int ch = (w * 2) + (nq >> 3);
            s_h2[ml * 128 + ((ch ^ (ml & 15)) << 3) + (nq & 7)]       = f2bf(hnl);
            s_h2[(ml + 1) * 128 + ((ch ^ ((ml + 1) & 15)) << 3) + (nq & 7)] = f2bf(hnh);
        }
        __syncthreads();   // B4: new h2 visible
        // output head: out[m, s, :] = h2_new @ Wout^T + bout -> LDS staging
        if (tid < 256) {
            int ml = tid >> 1, oc = tid & 1;
            const float* wr = s_wo + oc * 128;
            float s0 = 0.f, s1 = 0.f;
            int mx = ml & 15;
#pragma unroll
            for (int c = 0; c < 16; ++c) {
                int base = ml * 128 + ((c ^ mx) << 3);
                int k0 = c << 3;
#pragma unroll
                for (int j = 0; j < 8; j += 2) {
                    unsigned u = *(const unsigned*)&s_h2[base + j];
                    s0 += bf2f((unsigned short)u) * wr[k0 + j];
                    s1 += bf2f((unsigned short)(u >> 16)) * wr[k0 + j + 1];
                }
            }
            s_out[ml * 24 + s * 2 + oc] = s0 + s1 + bo;
        }
    }
    __syncthreads();
    // single contiguous coalesced store: 128 samples x 24 floats = 12 KB
    for (int i = tid; i < 3072; i += 512) out[m0 * 24 + i] = s_out[i];
}

extern "C" void kernel_launch(void* const* d_in, const int* in_sizes, int n_in,
                              void* d_out, int out_size, void* d_ws, size_t ws_size,
                              hipStream_t stream) {
    const float* fused  = (const float*)d_in[0];
    const float* intent = (const float*)d_in[1];
    const float* Winit  = (const float*)d_in[2];
    const float* binit  = (const float*)d_in[3];
    const float* Wihl0  = (const float*)d_in[4];
    const float* Whhl0  = (const float*)d_in[5];
    const float* bihl0  = (const float*)d_in[6];
    const float* bhhl0  = (const float*)d_in[7];
    const float* Wihl1  = (const float*)d_in[8];
    const float* Whhl1  = (const float*)d_in[9];
    const float* bihl1  = (const float*)d_in[10];
    const float* bhhl1  = (const float*)d_in[11];
    const float* Wout   = (const float*)d_in[12];
    const float* bout   = (const float*)d_in[13];
    int Bsz = in_sizes[0] / 128;

    // replicate packed weights (pow2 <= 8, limited by ws_size)
    int ncopy = 1;
    while (ncopy < 8 && (size_t)(ncopy * 2) * 655360ull <= ws_size) ncopy <<= 1;

    unsigned short* pkw = (unsigned short*)d_ws;   // ncopy * 640 KB used
    pack_w<<<1280, 256, 0, stream>>>(Winit, Wihl0, Whhl0, Wihl1, Whhl1, pkw, ncopy);
    traj_main<<<Bsz / 128, 512, 0, stream>>>(fused, intent, binit, Winit, Wihl0, bihl0,
                                             bhhl0, bihl1, bhhl1, Wout, bout, pkw,
                                             ncopy - 1, (float*)d_out, Bsz);
}